// Round 6
// baseline (449.363 us; speedup 1.0000x reference)
//
#include <hip/hip_runtime.h>

// Problem constants (match reference file)
#define N_NODES 2000000
#define N_EDGES 32000000
#define N_OUT   400000          // N_NODES / 5
#define NBUCKET 256             // out-index buckets
#define BSZ     1568            // bucket width: 256*1568 = 401408 >= 400000; local fits 11 bits
#define CAP_BLK 16              // per-block per-bucket LDS staging capacity (u32)
#define CHUNK   8192            // edges per block, phase 1 (256 thr * 4 edges * 8 iters)
#define CAP_BKT 28672           // per-bucket payload capacity (lambda=25000, +23 sigma)
#define CNT_STRIDE 16           // pad cursor counters: one per 64B cacheline

typedef int iv4 __attribute__((ext_vector_type(4)));
typedef unsigned uv4 __attribute__((ext_vector_type(4)));

// ---------------------------------------------------------------------------
// Phase 1: bin filtered edges into 256 buckets by out-index.
// payload u32 = (src << 11) | local, src < 2^21, local < 1568 < 2^11.
// Occupancy is the lever: CAP_BLK=16 + CHUNK=8192 -> LDS 19.5 KB ->
// 8 blocks/CU = 32 waves/CU (launch_bounds(256,8) caps VGPR at 64).
// The exec-masked ds_add_rtn/ds_write chain is latency-exposed; TLP is the
// only thing that hides it (R0->R1 occupancy doubling was the largest
// verified gain; source-level reordering attempts returned ~5 us each).
// Overflow safety at CAP 16: lambda = 6.4 passing edges/bucket/block,
// P(X>16) ~ 2.5e-4 -> ~250 overflow events device-wide, negligible.
// Batch-then-commit: classify 4 edges, issue 4 cursor atomics back-to-back,
// then commit stores (one lgkmcnt wait per group).
// s_stage row stride CAP_BLK+1=17 (odd): bank = (17*b + slot) % 32 -> spread.
// Filter via multiplicative inverse: t = d * 0xCCCCCCCD;
// d%5==0  <=>  t <= 0x33333333, and then t == d/5 exactly.
// ---------------------------------------------------------------------------
__global__ __launch_bounds__(256, 8) void p1_bin(
    const int* __restrict__ src,
    const int* __restrict__ dst,
    const float* __restrict__ x,
    unsigned* __restrict__ cnt,        // [NBUCKET * CNT_STRIDE]
    float* __restrict__ overflow,      // [NBUCKET][BSZ]
    unsigned* __restrict__ payload)    // [NBUCKET][CAP_BKT]
{
    __shared__ unsigned s_cur[NBUCKET];
    __shared__ unsigned s_base[NBUCKET];
    __shared__ unsigned s_stage[NBUCKET][CAP_BLK + 1];   // stride 17: bank spread

    const int tid = threadIdx.x;
    if (tid < NBUCKET) s_cur[tid] = 0;
    __syncthreads();

    const long long blockStart = (long long)blockIdx.x * CHUNK;
    const int NIT = CHUNK / 1024;   // 8 iterations; 1024 edges (4/thread) per iter

    // software-pipelined streaming: prefetch next iter's int4 pair.
    // nontemporal: edges are read exactly once.
    long long b0 = blockStart + (long long)tid * 4;
    bool valid0 = (b0 < N_EDGES);
    iv4 d4 = (iv4)0, s4 = (iv4)0;
    if (valid0) {
        d4 = __builtin_nontemporal_load(reinterpret_cast<const iv4*>(dst + b0));
        s4 = __builtin_nontemporal_load(reinterpret_cast<const iv4*>(src + b0));
    }

    for (int it = 0; it < NIT; ++it) {
        iv4 nd = (iv4)0, ns = (iv4)0;
        bool nvalid = false;
        if (it + 1 < NIT) {
            const long long bn = blockStart + (long long)(it + 1) * 1024 + tid * 4;
            nvalid = (bn < N_EDGES);
            if (nvalid) {
                nd = __builtin_nontemporal_load(reinterpret_cast<const iv4*>(dst + bn));
                ns = __builtin_nontemporal_load(reinterpret_cast<const iv4*>(src + bn));
            }
        }
        if (valid0) {
            // ---- classify all 4 edges (pure VALU, no LDS) ----
            bool     ps[4];
            unsigned bb[4], pp[4];
#pragma unroll
            for (int j = 0; j < 4; ++j) {
                const unsigned d = (unsigned)d4[j];
                const unsigned s = (unsigned)s4[j];
                const unsigned t = d * 0xCCCCCCCDu;      // == d/5 when d%5==0
                ps[j] = (t <= 0x33333333u);
                const unsigned q = t / (unsigned)BSZ;    // magic mul, full-range
                bb[j] = q & 255u;                        // exact for passing lanes
                const unsigned local = t - q * (unsigned)BSZ;   // always < 1568
                pp[j] = (s << 11) | local;
            }
            // ---- issue all cursor atomics back-to-back (slot unused yet) ----
            unsigned slot[4];
#pragma unroll
            for (int j = 0; j < 4; ++j)
                if (ps[j]) slot[j] = atomicAdd(&s_cur[bb[j]], 1u);
            // ---- commit: one lgkmcnt wait covers the group ----
#pragma unroll
            for (int j = 0; j < 4; ++j) {
                if (ps[j]) {
                    if (slot[j] < CAP_BLK) {
                        s_stage[bb[j]][slot[j]] = pp[j];
                    } else {
                        // rare (~2.5e-4 per bucket-block): device-scope overflow add
                        atomicAdd(&overflow[(size_t)bb[j] * BSZ + (pp[j] & 2047u)],
                                  x[pp[j] >> 11]);
                    }
                }
            }
        }
        d4 = nd; s4 = ns; valid0 = nvalid;
    }
    __syncthreads();

    // reserve payload runs: 256 parallel cursor atomics (one 64B line each)
    if (tid < NBUCKET) {
        const unsigned c = min(s_cur[tid], (unsigned)CAP_BLK);
        s_cur[tid] = c;
        s_base[tid] = atomicAdd(&cnt[tid * CNT_STRIDE], c);
    }
    __syncthreads();

    // flush: each wave handles 64 buckets, four per step (16 lanes each)
    const int wave = tid >> 6, lane = tid & 63;
    const int quarter = lane >> 4, l = lane & 15;
    for (int i = 0; i < 16; ++i) {
        const int b = wave * 64 + i * 4 + quarter;
        const unsigned c = s_cur[b];
        const unsigned pos = s_base[b] + (unsigned)l;
        if ((unsigned)l < c && pos < (unsigned)CAP_BKT)
            payload[(size_t)b * CAP_BKT + pos] = s_stage[b][l];
    }
}

// ---------------------------------------------------------------------------
// Phase 2 (fused with epilogue): one 1024-thread block per bucket.
// 2-deep pipelined payload stream (next batch's 32B loads issue before the
// current batch's gathers), gather x 8-deep, ds_add_f32 into the 1568-float
// LDS accumulator, then overflow row + folded affine + 2->4->1 MLP, write
// out[b*BSZ ..] directly.
// ---------------------------------------------------------------------------
__global__ __launch_bounds__(1024, 4) void p2_fused(
    const unsigned* __restrict__ cnt,
    const unsigned* __restrict__ payload,
    const float* __restrict__ x,
    const float* __restrict__ overflow,
    const float* __restrict__ w_conv,
    const float* __restrict__ b_conv,
    const float* __restrict__ w1,   // [2,4] row-major
    const float* __restrict__ b1,
    const float* __restrict__ w2,
    const float* __restrict__ b2,
    float* __restrict__ out)
{
    __shared__ float acc[BSZ];
    const int b = blockIdx.x;
    const int tid = threadIdx.x;

    for (int i = tid; i < BSZ; i += 1024) acc[i] = 0.0f;
    __syncthreads();

    unsigned n = cnt[b * CNT_STRIDE];
    if (n > CAP_BKT) n = CAP_BKT;         // safety clamp (never expected)
    const unsigned* pb = payload + (size_t)b * CAP_BKT;

    // 8 entries (32B) per thread per step, 2-deep software pipeline
    unsigned i0 = (unsigned)tid * 8u;
    uv4 A = {}, B = {};
    bool cur = (i0 + 7u < n);
    if (cur) {
        A = __builtin_nontemporal_load(reinterpret_cast<const uv4*>(pb + i0));
        B = __builtin_nontemporal_load(reinterpret_cast<const uv4*>(pb + i0 + 4));
    }
    while (cur) {
        const unsigned i1 = i0 + 1024u * 8u;
        uv4 nA = {}, nB = {};
        const bool nxt = (i1 + 7u < n);
        if (nxt) {
            nA = __builtin_nontemporal_load(reinterpret_cast<const uv4*>(pb + i1));
            nB = __builtin_nontemporal_load(reinterpret_cast<const uv4*>(pb + i1 + 4));
        }
        unsigned pv[8];
#pragma unroll
        for (int u = 0; u < 4; ++u) { pv[u] = A[u]; pv[u + 4] = B[u]; }
        float vv[8];
#pragma unroll
        for (int u = 0; u < 8; ++u) vv[u] = x[pv[u] >> 11];
#pragma unroll
        for (int u = 0; u < 8; ++u)
            __hip_atomic_fetch_add(&acc[pv[u] & 2047u], vv[u],
                                   __ATOMIC_RELAXED, __HIP_MEMORY_SCOPE_WORKGROUP);
        A = nA; B = nB; i0 = i1; cur = nxt;
    }
    if (i0 < n) {                          // per-thread ragged tail (< 8 entries)
        const unsigned stop = min(n, i0 + 8u);
        for (unsigned i = i0; i < stop; ++i) {
            const unsigned p = pb[i];
            __hip_atomic_fetch_add(&acc[p & 2047u], x[p >> 11],
                                   __ATOMIC_RELAXED, __HIP_MEMORY_SCOPE_WORKGROUP);
        }
    }
    __syncthreads();

    // epilogue: overflow add + folded affine + MLP, coalesced out write
    const float wc = w_conv[0], bc = b_conv[0], bb2 = b2[0];
    float w1s[4], bb1[4], ww2[4];
#pragma unroll
    for (int jj = 0; jj < 4; ++jj) {
        w1s[jj] = w1[jj] + w1[4 + jj];
        bb1[jj] = b1[jj];
        ww2[jj] = w2[jj];
    }
    const int gbase = b * BSZ;
    for (int local = tid; local < BSZ; local += 1024) {
        const int gi = gbase + local;
        if (gi < N_OUT) {
            const float s = acc[local] + overflow[(size_t)b * BSZ + local];
            const float a = s * wc + bc;
            float rr = bb2;
#pragma unroll
            for (int jj = 0; jj < 4; ++jj) {
                const float tt = fmaf(a, w1s[jj], bb1[jj]);
                rr = fmaf(fmaxf(tt, 0.0f), ww2[jj], rr);
            }
            out[gi] = rr;
        }
    }
}

// ---------------------------------------------------------------------------
// Fallback (ws too small): direct device-atomic scatter + epilogue.
// ---------------------------------------------------------------------------
__global__ __launch_bounds__(256, 4) void gcn_edge_scatter_dev(
    const int* __restrict__ src,
    const int* __restrict__ dst,
    const float* __restrict__ x,
    float* __restrict__ agg)
{
    const long long base = ((long long)blockIdx.x * blockDim.x + threadIdx.x) * 16;
    if (base >= N_EDGES) return;
    iv4 d4[4], s4[4];
#pragma unroll
    for (int c = 0; c < 4; ++c)
        d4[c] = *(reinterpret_cast<const iv4*>(dst + base) + c);
#pragma unroll
    for (int c = 0; c < 4; ++c)
        s4[c] = *(reinterpret_cast<const iv4*>(src + base) + c);
    int dd[16]; int idx[16]; bool pass[16];
#pragma unroll
    for (int c = 0; c < 4; ++c)
#pragma unroll
        for (int j = 0; j < 4; ++j) {
            const int d = d4[c][j];
            const bool p = (d % 5 == 0);
            dd[c * 4 + j] = d; pass[c * 4 + j] = p;
            idx[c * 4 + j] = p ? s4[c][j] : 0;
        }
    float v[16];
#pragma unroll
    for (int k = 0; k < 16; ++k) v[k] = x[idx[k]];
#pragma unroll
    for (int k = 0; k < 16; ++k)
        if (pass[k]) atomicAdd(&agg[dd[k] / 5], v[k]);
}

__global__ __launch_bounds__(256) void gcn_epilogue_fb(
    const float* __restrict__ agg,
    const float* __restrict__ w_conv, const float* __restrict__ b_conv,
    const float* __restrict__ w1, const float* __restrict__ b1,
    const float* __restrict__ w2, const float* __restrict__ b2,
    float* __restrict__ out)
{
    const int i = blockIdx.x * 256 + threadIdx.x;
    if (i >= N_OUT) return;
    const float a = agg[i] * w_conv[0] + b_conv[0];
    float r = b2[0];
#pragma unroll
    for (int j = 0; j < 4; ++j) {
        float t = fmaf(a, w1[j] + w1[4 + j], b1[j]);
        r = fmaf(fmaxf(t, 0.0f), w2[j], r);
    }
    out[i] = r;
}

extern "C" void kernel_launch(void* const* d_in, const int* in_sizes, int n_in,
                              void* d_out, int out_size, void* d_ws, size_t ws_size,
                              hipStream_t stream) {
    const float* x      = (const float*)d_in[0];
    const int*   ei     = (const int*)  d_in[1];  // [2, N_EDGES]: src row then dst row
    const float* w_conv = (const float*)d_in[2];
    const float* b_conv = (const float*)d_in[3];
    const float* w1     = (const float*)d_in[4];
    const float* b1     = (const float*)d_in[5];
    const float* w2     = (const float*)d_in[6];
    const float* b2     = (const float*)d_in[7];
    float* out = (float*)d_out;

    // ws layout: [cnt 16KB][overflow 1.6MB][payload 25.6MB]
    // Only cnt + overflow need zeroing.
    const size_t cnt_bytes = (size_t)NBUCKET * CNT_STRIDE * sizeof(unsigned); // 16384
    const size_t ovf_off   = cnt_bytes;
    const size_t ovf_bytes = (size_t)NBUCKET * BSZ * sizeof(float);           // 1605632
    const size_t pay_off   = (ovf_off + ovf_bytes + 255) & ~(size_t)255;
    const size_t pay_bytes = (size_t)NBUCKET * CAP_BKT * sizeof(unsigned);    // 29360128
    const size_t need      = pay_off + pay_bytes;

    if (ws_size >= need) {
        unsigned* cnt      = (unsigned*)d_ws;
        float*    overflow = (float*)((char*)d_ws + ovf_off);
        unsigned* payload  = (unsigned*)((char*)d_ws + pay_off);

        (void)hipMemsetAsync(d_ws, 0, ovf_off + ovf_bytes, stream); // cnt + overflow

        const int grid_p1 = (int)((N_EDGES + CHUNK - 1) / CHUNK);   // 3907
        p1_bin<<<grid_p1, 256, 0, stream>>>(ei, ei + N_EDGES, x, cnt, overflow, payload);
        p2_fused<<<NBUCKET, 1024, 0, stream>>>(
            cnt, payload, x, overflow, w_conv, b_conv, w1, b1, w2, b2, out);
    } else {
        float* agg = (float*)d_ws;
        (void)hipMemsetAsync(agg, 0, (size_t)N_OUT * sizeof(float), stream);
        gcn_edge_scatter_dev<<<(N_EDGES / 16 + 255) / 256, 256, 0, stream>>>(
            ei, ei + N_EDGES, x, agg);
        gcn_epilogue_fb<<<(N_OUT + 255) / 256, 256, 0, stream>>>(
            agg, w_conv, b_conv, w1, b1, w2, b2, out);
    }
}

// Round 7
// 438.649 us; speedup vs baseline: 1.0244x; 1.0244x over previous
//
#include <hip/hip_runtime.h>

// Problem constants (match reference file)
#define N_NODES 2000000
#define N_EDGES 32000000
#define N_OUT   400000          // N_NODES / 5
#define NBUCKET 256             // out-index buckets
#define BSZ     1568            // bucket width: 256*1568 = 401408 >= 400000; local fits 11 bits
#define CAP_BLK 32              // per-block per-bucket LDS staging capacity (u32)
#define CHUNK   16384           // edges per block, phase 1 (256 thr * 8 edges * 8 iters)
#define CAP_BKT 28672           // per-bucket payload capacity (lambda=25000, +23 sigma)
#define CNT_STRIDE 16           // pad cursor counters: one per 64B cacheline

typedef int iv4 __attribute__((ext_vector_type(4)));
typedef unsigned uv4 __attribute__((ext_vector_type(4)));

// ---------------------------------------------------------------------------
// Phase 1: bin filtered edges into 256 buckets by out-index.
// payload u32 = (src << 11) | local, src < 2^21, local < 1568 < 2^11.
// OCCUPANCY OPTIMUM IS 4 BLOCKS/CU (measured): 2 blocks/CU (R0, 66KB LDS)
// = 457us; 4 blocks/CU (R4, 35.8KB) = 436.6us; 8 blocks/CU (R6, 19.5KB,
// 2x grid) = 449.4us — per-block fixed costs (LDS init, 256 cursor
// atomics, flush overhead) outweigh added TLP beyond 4.
// Batch-then-commit staging: per iteration each thread classifies 8 edges,
// issues all 8 exec-masked ds_add_rtn cursor atomics back-to-back (slot is
// not consumed until the store loop, so only ONE lgkmcnt wait per iteration
// instead of 8 serialized atomic->wait->store chains), then commits stores.
// s_stage row stride CAP_BLK+1=33: bank = (bucket + slot) % 32 -> spread.
// LDS 35.8 KB -> 4 blocks/CU.
// Filter via multiplicative inverse: t = d * 0xCCCCCCCD;
// d%5==0  <=>  t <= 0x33333333, and then t == d/5 exactly.
// ---------------------------------------------------------------------------
__global__ __launch_bounds__(256, 4) void p1_bin(
    const int* __restrict__ src,
    const int* __restrict__ dst,
    const float* __restrict__ x,
    unsigned* __restrict__ cnt,        // [NBUCKET * CNT_STRIDE]
    float* __restrict__ overflow,      // [NBUCKET][BSZ]
    unsigned* __restrict__ payload)    // [NBUCKET][CAP_BKT]
{
    __shared__ unsigned s_cur[NBUCKET];
    __shared__ unsigned s_base[NBUCKET];
    __shared__ unsigned s_stage[NBUCKET][CAP_BLK + 1];   // stride 33: bank spread

    const int tid = threadIdx.x;
    if (tid < NBUCKET) s_cur[tid] = 0;
    __syncthreads();

    const long long blockStart = (long long)blockIdx.x * CHUNK;
    const int NIT = CHUNK / 2048;   // 8 iterations; 2048 edges (8/thread) per iter

    // software-pipelined streaming: prefetch next iter's two int4 pairs.
    // nontemporal: edges are read exactly once. N_EDGES % 8 == 0, so an
    // 8-edge group is either fully in range or fully out.
    long long b0 = blockStart + (long long)tid * 8;
    bool valid0 = (b0 < N_EDGES);
    iv4 dA = (iv4)0, dB = (iv4)0, sA = (iv4)0, sB = (iv4)0;
    if (valid0) {
        dA = __builtin_nontemporal_load(reinterpret_cast<const iv4*>(dst + b0));
        dB = __builtin_nontemporal_load(reinterpret_cast<const iv4*>(dst + b0 + 4));
        sA = __builtin_nontemporal_load(reinterpret_cast<const iv4*>(src + b0));
        sB = __builtin_nontemporal_load(reinterpret_cast<const iv4*>(src + b0 + 4));
    }

    for (int it = 0; it < NIT; ++it) {
        iv4 ndA = (iv4)0, ndB = (iv4)0, nsA = (iv4)0, nsB = (iv4)0;
        bool nvalid = false;
        if (it + 1 < NIT) {
            const long long bn = blockStart + (long long)(it + 1) * 2048 + tid * 8;
            nvalid = (bn < N_EDGES);
            if (nvalid) {
                ndA = __builtin_nontemporal_load(reinterpret_cast<const iv4*>(dst + bn));
                ndB = __builtin_nontemporal_load(reinterpret_cast<const iv4*>(dst + bn + 4));
                nsA = __builtin_nontemporal_load(reinterpret_cast<const iv4*>(src + bn));
                nsB = __builtin_nontemporal_load(reinterpret_cast<const iv4*>(src + bn + 4));
            }
        }
        if (valid0) {
            // ---- classify all 8 edges (pure VALU, no LDS) ----
            bool     ps[8];
            unsigned bb[8], pp[8];
#pragma unroll
            for (int j = 0; j < 8; ++j) {
                const unsigned d = (unsigned)(j < 4 ? dA[j] : dB[j - 4]);
                const unsigned s = (unsigned)(j < 4 ? sA[j] : sB[j - 4]);
                const unsigned t = d * 0xCCCCCCCDu;      // == d/5 when d%5==0
                ps[j] = (t <= 0x33333333u);
                const unsigned q = t / (unsigned)BSZ;    // magic mul, full-range
                bb[j] = q & 255u;                        // exact for passing lanes
                const unsigned local = t - q * (unsigned)BSZ;   // always < 1568
                pp[j] = (s << 11) | local;
            }
            // ---- issue all cursor atomics back-to-back (slot unused yet) ----
            unsigned slot[8];
#pragma unroll
            for (int j = 0; j < 8; ++j)
                if (ps[j]) slot[j] = atomicAdd(&s_cur[bb[j]], 1u);
            // ---- commit: one lgkmcnt wait covers all 8 atomics ----
#pragma unroll
            for (int j = 0; j < 8; ++j) {
                if (ps[j]) {
                    if (slot[j] < CAP_BLK) {
                        s_stage[bb[j]][slot[j]] = pp[j];
                    } else {
                        // rare (~5 sigma): direct device-scope add into overflow row
                        atomicAdd(&overflow[(size_t)bb[j] * BSZ + (pp[j] & 2047u)],
                                  x[pp[j] >> 11]);
                    }
                }
            }
        }
        dA = ndA; dB = ndB; sA = nsA; sB = nsB; valid0 = nvalid;
    }
    __syncthreads();

    // reserve payload runs: 256 parallel cursor atomics (one 64B line each)
    if (tid < NBUCKET) {
        const unsigned c = min(s_cur[tid], (unsigned)CAP_BLK);
        s_cur[tid] = c;
        s_base[tid] = atomicAdd(&cnt[tid * CNT_STRIDE], c);
    }
    __syncthreads();

    // flush: each wave handles 64 buckets, two per step (32 lanes each)
    const int wave = tid >> 6, lane = tid & 63;
    const int half = lane >> 5, l = lane & 31;
    for (int i = 0; i < 32; ++i) {
        const int b = wave * 64 + i * 2 + half;
        const unsigned c = s_cur[b];
        const unsigned pos = s_base[b] + (unsigned)l;
        if ((unsigned)l < c && pos < (unsigned)CAP_BKT)
            payload[(size_t)b * CAP_BKT + pos] = s_stage[b][l];
    }
}

// ---------------------------------------------------------------------------
// Phase 2 (fused with epilogue): one 1024-thread block per bucket.
// 2-deep pipelined payload stream (next batch's 32B loads issue before the
// current batch's gathers), gather x 8-deep, ds_add_f32 into the 1568-float
// LDS accumulator, then overflow row + folded affine + 2->4->1 MLP, write
// out[b*BSZ ..] directly.
// ---------------------------------------------------------------------------
__global__ __launch_bounds__(1024, 4) void p2_fused(
    const unsigned* __restrict__ cnt,
    const unsigned* __restrict__ payload,
    const float* __restrict__ x,
    const float* __restrict__ overflow,
    const float* __restrict__ w_conv,
    const float* __restrict__ b_conv,
    const float* __restrict__ w1,   // [2,4] row-major
    const float* __restrict__ b1,
    const float* __restrict__ w2,
    const float* __restrict__ b2,
    float* __restrict__ out)
{
    __shared__ float acc[BSZ];
    const int b = blockIdx.x;
    const int tid = threadIdx.x;

    for (int i = tid; i < BSZ; i += 1024) acc[i] = 0.0f;
    __syncthreads();

    unsigned n = cnt[b * CNT_STRIDE];
    if (n > CAP_BKT) n = CAP_BKT;         // safety clamp (never expected)
    const unsigned* pb = payload + (size_t)b * CAP_BKT;

    // 8 entries (32B) per thread per step, 2-deep software pipeline
    unsigned i0 = (unsigned)tid * 8u;
    uv4 A = {}, B = {};
    bool cur = (i0 + 7u < n);
    if (cur) {
        A = __builtin_nontemporal_load(reinterpret_cast<const uv4*>(pb + i0));
        B = __builtin_nontemporal_load(reinterpret_cast<const uv4*>(pb + i0 + 4));
    }
    while (cur) {
        const unsigned i1 = i0 + 1024u * 8u;
        uv4 nA = {}, nB = {};
        const bool nxt = (i1 + 7u < n);
        if (nxt) {
            nA = __builtin_nontemporal_load(reinterpret_cast<const uv4*>(pb + i1));
            nB = __builtin_nontemporal_load(reinterpret_cast<const uv4*>(pb + i1 + 4));
        }
        unsigned pv[8];
#pragma unroll
        for (int u = 0; u < 4; ++u) { pv[u] = A[u]; pv[u + 4] = B[u]; }
        float vv[8];
#pragma unroll
        for (int u = 0; u < 8; ++u) vv[u] = x[pv[u] >> 11];
#pragma unroll
        for (int u = 0; u < 8; ++u)
            __hip_atomic_fetch_add(&acc[pv[u] & 2047u], vv[u],
                                   __ATOMIC_RELAXED, __HIP_MEMORY_SCOPE_WORKGROUP);
        A = nA; B = nB; i0 = i1; cur = nxt;
    }
    if (i0 < n) {                          // per-thread ragged tail (< 8 entries)
        const unsigned stop = min(n, i0 + 8u);
        for (unsigned i = i0; i < stop; ++i) {
            const unsigned p = pb[i];
            __hip_atomic_fetch_add(&acc[p & 2047u], x[p >> 11],
                                   __ATOMIC_RELAXED, __HIP_MEMORY_SCOPE_WORKGROUP);
        }
    }
    __syncthreads();

    // epilogue: overflow add + folded affine + MLP, coalesced out write
    const float wc = w_conv[0], bc = b_conv[0], bb2 = b2[0];
    float w1s[4], bb1[4], ww2[4];
#pragma unroll
    for (int jj = 0; jj < 4; ++jj) {
        w1s[jj] = w1[jj] + w1[4 + jj];
        bb1[jj] = b1[jj];
        ww2[jj] = w2[jj];
    }
    const int gbase = b * BSZ;
    for (int local = tid; local < BSZ; local += 1024) {
        const int gi = gbase + local;
        if (gi < N_OUT) {
            const float s = acc[local] + overflow[(size_t)b * BSZ + local];
            const float a = s * wc + bc;
            float rr = bb2;
#pragma unroll
            for (int jj = 0; jj < 4; ++jj) {
                const float tt = fmaf(a, w1s[jj], bb1[jj]);
                rr = fmaf(fmaxf(tt, 0.0f), ww2[jj], rr);
            }
            out[gi] = rr;
        }
    }
}

// ---------------------------------------------------------------------------
// Fallback (ws too small): direct device-atomic scatter + epilogue.
// ---------------------------------------------------------------------------
__global__ __launch_bounds__(256, 4) void gcn_edge_scatter_dev(
    const int* __restrict__ src,
    const int* __restrict__ dst,
    const float* __restrict__ x,
    float* __restrict__ agg)
{
    const long long base = ((long long)blockIdx.x * blockDim.x + threadIdx.x) * 16;
    if (base >= N_EDGES) return;
    iv4 d4[4], s4[4];
#pragma unroll
    for (int c = 0; c < 4; ++c)
        d4[c] = *(reinterpret_cast<const iv4*>(dst + base) + c);
#pragma unroll
    for (int c = 0; c < 4; ++c)
        s4[c] = *(reinterpret_cast<const iv4*>(src + base) + c);
    int dd[16]; int idx[16]; bool pass[16];
#pragma unroll
    for (int c = 0; c < 4; ++c)
#pragma unroll
        for (int j = 0; j < 4; ++j) {
            const int d = d4[c][j];
            const bool p = (d % 5 == 0);
            dd[c * 4 + j] = d; pass[c * 4 + j] = p;
            idx[c * 4 + j] = p ? s4[c][j] : 0;
        }
    float v[16];
#pragma unroll
    for (int k = 0; k < 16; ++k) v[k] = x[idx[k]];
#pragma unroll
    for (int k = 0; k < 16; ++k)
        if (pass[k]) atomicAdd(&agg[dd[k] / 5], v[k]);
}

__global__ __launch_bounds__(256) void gcn_epilogue_fb(
    const float* __restrict__ agg,
    const float* __restrict__ w_conv, const float* __restrict__ b_conv,
    const float* __restrict__ w1, const float* __restrict__ b1,
    const float* __restrict__ w2, const float* __restrict__ b2,
    float* __restrict__ out)
{
    const int i = blockIdx.x * 256 + threadIdx.x;
    if (i >= N_OUT) return;
    const float a = agg[i] * w_conv[0] + b_conv[0];
    float r = b2[0];
#pragma unroll
    for (int j = 0; j < 4; ++j) {
        float t = fmaf(a, w1[j] + w1[4 + j], b1[j]);
        r = fmaf(fmaxf(t, 0.0f), w2[j], r);
    }
    out[i] = r;
}

extern "C" void kernel_launch(void* const* d_in, const int* in_sizes, int n_in,
                              void* d_out, int out_size, void* d_ws, size_t ws_size,
                              hipStream_t stream) {
    const float* x      = (const float*)d_in[0];
    const int*   ei     = (const int*)  d_in[1];  // [2, N_EDGES]: src row then dst row
    const float* w_conv = (const float*)d_in[2];
    const float* b_conv = (const float*)d_in[3];
    const float* w1     = (const float*)d_in[4];
    const float* b1     = (const float*)d_in[5];
    const float* w2     = (const float*)d_in[6];
    const float* b2     = (const float*)d_in[7];
    float* out = (float*)d_out;

    // ws layout: [cnt 16KB][overflow 1.6MB][payload 25.6MB]
    // Only cnt + overflow need zeroing.
    const size_t cnt_bytes = (size_t)NBUCKET * CNT_STRIDE * sizeof(unsigned); // 16384
    const size_t ovf_off   = cnt_bytes;
    const size_t ovf_bytes = (size_t)NBUCKET * BSZ * sizeof(float);           // 1605632
    const size_t pay_off   = (ovf_off + ovf_bytes + 255) & ~(size_t)255;
    const size_t pay_bytes = (size_t)NBUCKET * CAP_BKT * sizeof(unsigned);    // 29360128
    const size_t need      = pay_off + pay_bytes;

    if (ws_size >= need) {
        unsigned* cnt      = (unsigned*)d_ws;
        float*    overflow = (float*)((char*)d_ws + ovf_off);
        unsigned* payload  = (unsigned*)((char*)d_ws + pay_off);

        (void)hipMemsetAsync(d_ws, 0, ovf_off + ovf_bytes, stream); // cnt + overflow

        const int grid_p1 = (int)((N_EDGES + CHUNK - 1) / CHUNK);   // 1954
        p1_bin<<<grid_p1, 256, 0, stream>>>(ei, ei + N_EDGES, x, cnt, overflow, payload);
        p2_fused<<<NBUCKET, 1024, 0, stream>>>(
            cnt, payload, x, overflow, w_conv, b_conv, w1, b1, w2, b2, out);
    } else {
        float* agg = (float*)d_ws;
        (void)hipMemsetAsync(agg, 0, (size_t)N_OUT * sizeof(float), stream);
        gcn_edge_scatter_dev<<<(N_EDGES / 16 + 255) / 256, 256, 0, stream>>>(
            ei, ei + N_EDGES, x, agg);
        gcn_epilogue_fb<<<(N_OUT + 255) / 256, 256, 0, stream>>>(
            agg, w_conv, b_conv, w1, b1, w2, b2, out);
    }
}